// Round 8
// baseline (76.474 us; speedup 1.0000x reference)
//
#include <hip/hip_runtime.h>
#include <math.h>

#define NN   8192
#define R    8              // rows per block
#define GX   (NN / R)       // 1024 blocks = 4/CU = 16 waves/CU = 4 waves/SIMD
#define EPSF 1e-6f

// ws layout:
//   pack2[NN] : uint2 {T_f32, bf16(er) | bf16(es)<<16}   (65536 B)
//   sumR[NN]  : float                                     (32768 B)
//   sumS[NN]  : float                                     (32768 B)
// Every slot written every call (0xAA poison safe). No atomics/fences:
// cross-kernel visibility via kernel boundaries (R3/R5-proven).

__device__ __forceinline__ unsigned bf16_rne(float x) {
  unsigned u = __float_as_uint(x);
  u += 0x7fffu + ((u >> 16) & 1u);   // round-to-nearest-even; x finite >= 0
  return u >> 16;
}

__global__ __launch_bounds__(256) void ds_prep(
    const float* __restrict__ Pr, const float* __restrict__ Ps,
    const float* __restrict__ T,  const int* __restrict__ E,
    uint2* __restrict__ pack2) {
  int i = blockIdx.x * 256 + threadIdx.x;
  float t  = T[i];
  float er = __expf(Pr[i]);
  float es = E[i] ? __expf(Ps[i]) : 0.0f;
  unsigned c = bf16_rne(er) | (bf16_rne(es) << 16);  // er low16, es high16
  pack2[i] = make_uint2(__float_as_uint(t), c);
}

// O(N^2) pass: block owns rows [b*8, b*8+8), streams all j at 8 B/j.
// One int4 = 2 j-elements; 16 loads total per thread, fully unrolled for MLP.
__global__ __launch_bounds__(256, 4) void ds_main(
    const float* __restrict__ T, const int4* __restrict__ pack2,
    float* __restrict__ sumR, float* __restrict__ sumS) {
  const int tid  = threadIdx.x;
  const int row0 = blockIdx.x * R;

  float Ti[R];
#pragma unroll
  for (int r = 0; r < R; ++r) Ti[r] = T[row0 + r];   // block-uniform -> s_load

  float sr[R], ss[R];
#pragma unroll
  for (int r = 0; r < R; ++r) { sr[r] = 0.0f; ss[r] = 0.0f; }

#pragma unroll
  for (int it = 0; it < 4; ++it) {
    const int m = it * 1024 + tid;       // int4 index; 2 j per int4
    int4 q0 = pack2[m];
    int4 q1 = pack2[m + 256];
    int4 q2 = pack2[m + 512];
    int4 q3 = pack2[m + 768];
#pragma unroll
    for (int q = 0; q < 4; ++q) {
      int4 p = (q == 0) ? q0 : (q == 1) ? q1 : (q == 2) ? q2 : q3;
      float    t0 = __int_as_float(p.x);
      unsigned c0 = (unsigned)p.y;
      float    er0 = __uint_as_float(c0 << 16);
      float    es0 = __uint_as_float(c0 & 0xffff0000u);
      float    t1 = __int_as_float(p.z);
      unsigned c1 = (unsigned)p.w;
      float    er1 = __uint_as_float(c1 << 16);
      float    es1 = __uint_as_float(c1 & 0xffff0000u);
#pragma unroll
      for (int r = 0; r < R; ++r) {
        bool g0 = t0 > Ti[r];
        sr[r] += g0 ? er0 : 0.0f;   ss[r] += g0 ? 0.0f : es0;
        bool g1 = t1 > Ti[r];
        sr[r] += g1 ? er1 : 0.0f;   ss[r] += g1 ? 0.0f : es1;
      }
    }
  }

  // wave shuffle reduction, then cross-wave via LDS
#pragma unroll
  for (int r = 0; r < R; ++r) {
    for (int off = 32; off > 0; off >>= 1) {
      sr[r] += __shfl_down(sr[r], off);
      ss[r] += __shfl_down(ss[r], off);
    }
  }
  __shared__ float sh[4][2 * R];
  const int wid = tid >> 6, lane = tid & 63;
  if (lane == 0) {
#pragma unroll
    for (int r = 0; r < R; ++r) { sh[wid][r] = sr[r]; sh[wid][R + r] = ss[r]; }
  }
  __syncthreads();
  if (tid < 2 * R) {
    float v = sh[0][tid] + sh[1][tid] + sh[2][tid] + sh[3][tid];
    if (tid < R) sumR[row0 + tid] = v;           // strict >, diag excluded
    else         sumS[row0 + (tid - R)] = v;     // complement incl. diagonal
  }
}

__global__ __launch_bounds__(1024) void ds_finalize(
    const float* __restrict__ Pr, const float* __restrict__ Ps,
    const int* __restrict__ E,    const uint2* __restrict__ pack2,
    const float* __restrict__ sumR, const float* __restrict__ sumS,
    float* __restrict__ out) {
  float nr = 0.0f, dr = 0.0f, ns = 0.0f, nds = 0.0f;
  for (int i = threadIdx.x; i < NN; i += 1024) {
    const int e = E[i];
    const float prv = Pr[i], psv = Ps[i];
    // diagonal es: unpack the SAME bf16 value main accumulated -> exact cancel
    const float es_diag = __uint_as_float(pack2[i].y & 0xffff0000u);
    const float srv = sumR[i];
    const float ssv = sumS[i] - es_diag;
    const float wr  = (e != 0 && srv > 0.0f) ? 1.0f : 0.0f;
    const float wsv = (ssv > 0.0f) ? 1.0f : 0.0f;
    nr  += wr  * (prv - logf(srv + EPSF));
    dr  += wr;
    ns  += wsv * (psv - logf(ssv + EPSF));
    nds += wsv;
  }
  for (int off = 32; off > 0; off >>= 1) {
    nr  += __shfl_down(nr,  off);
    dr  += __shfl_down(dr,  off);
    ns  += __shfl_down(ns,  off);
    nds += __shfl_down(nds, off);
  }
  __shared__ float sh[4][16];
  const int wid = threadIdx.x >> 6, lane = threadIdx.x & 63;
  if (lane == 0) {
    sh[0][wid] = nr; sh[1][wid] = dr; sh[2][wid] = ns; sh[3][wid] = nds;
  }
  __syncthreads();
  if (threadIdx.x == 0) {
    float NR = 0, DR = 0, NS = 0, DS = 0;
#pragma unroll
    for (int w = 0; w < 16; ++w) {
      NR += sh[0][w]; DR += sh[1][w]; NS += sh[2][w]; DS += sh[3][w];
    }
    out[0] = -NR / DR;
    out[1] = -NS / DS;
  }
}

extern "C" void kernel_launch(void* const* d_in, const int* in_sizes, int n_in,
                              void* d_out, int out_size, void* d_ws, size_t ws_size,
                              hipStream_t stream) {
  const float* Pr = (const float*)d_in[0];
  const float* Ps = (const float*)d_in[1];
  const float* T  = (const float*)d_in[2];
  const int*   E  = (const int*)d_in[3];
  float* out = (float*)d_out;

  char*  ws    = (char*)d_ws;
  uint2* pack2 = (uint2*)ws;
  float* sumR  = (float*)(ws + (size_t)NN * sizeof(uint2));
  float* sumS  = sumR + NN;

  ds_prep<<<NN / 256, 256, 0, stream>>>(Pr, Ps, T, E, pack2);
  ds_main<<<GX, 256, 0, stream>>>(T, (const int4*)pack2, sumR, sumS);
  ds_finalize<<<1, 1024, 0, stream>>>(Pr, Ps, E, pack2, sumR, sumS, out);
}